// Round 1
// baseline (203.249 us; speedup 1.0000x reference)
//
#include <hip/hip_runtime.h>
#include <math.h>

#define ALPHA 26
#define ROW_PAD 32      // rn row stride in workspace (128 B, aligned for s_load_dwordx16)
#define TPB 256
#define TOK_PAD 27      // LDS token stride (gcd(27,32)=1 -> conflict-free-ish)

// Pre-kernel: row-L2-normalize the 26x26 rotor into workspace, rows padded to 32.
__global__ void rotor_norm_kernel(const float* __restrict__ rotor,
                                  float* __restrict__ rn) {
    int i = threadIdx.x;
    if (i < ALPHA) {
        float ss = 0.f;
        #pragma unroll
        for (int j = 0; j < ALPHA; ++j) {
            float v = rotor[i * ALPHA + j];
            ss += v * v;
        }
        float inv = 1.0f / sqrtf(ss);
        #pragma unroll
        for (int j = 0; j < ALPHA; ++j)
            rn[i * ROW_PAD + j] = rotor[i * ALPHA + j] * inv;
    }
}

// Main kernel: 1 token per thread, 256 tokens per block.
// out[tok][j] = softmax_j( sum_k x[tok][(k - r) mod 26] * rn[k][j] ),  r = (tok & 8191) % 26
// rn accesses are wave-uniform -> scalar loads (SGPR), amortized across all 64 lanes.
__global__ __launch_bounds__(TPB) void rotor_main(
        const float* __restrict__ x,
        const float* __restrict__ rn,
        float* __restrict__ out) {
    __shared__ float tile[TPB * TOK_PAD];

    const int tid = threadIdx.x;
    const long long blockTok = (long long)blockIdx.x * TPB;
    const float* gin = x + blockTok * ALPHA;
    float* gout = out + blockTok * ALPHA;

    // ---- Stage 256 tokens (6656 floats) into LDS, coalesced float2 ----
    // f even and ALPHA even => both halves of the float2 land in the same token.
    #pragma unroll
    for (int it = 0; it < 13; ++it) {
        int v = tid + it * TPB;         // float2 index within tile
        int f = v * 2;                  // float index
        int tok = f / ALPHA;            // constant divisor -> magic mul
        int el = f - tok * ALPHA;
        float2 d = *(const float2*)(gin + f);
        float* p = &tile[tok * TOK_PAD + el];
        p[0] = d.x;
        p[1] = d.y;
    }
    __syncthreads();

    // ---- Per-token rotated matmul, rn rows from SGPRs ----
    const int n = (int)blockTok + tid;  // global token id (< 2^20, fits int)
    const int s = n & 8191;             // S = 8192
    const int r = s % 26;               // shift (position == 1)

    float acc[ALPHA];
    #pragma unroll
    for (int j = 0; j < ALPHA; ++j) acc[j] = 0.f;

    const float* myx = &tile[tid * TOK_PAD];
    int idx = 26 - r; if (idx == 26) idx = 0;   // (0 - r) mod 26
    for (int k = 0; k < ALPHA; ++k) {
        float xk = myx[idx];
        ++idx; if (idx == ALPHA) idx = 0;
        const float* row = rn + k * ROW_PAD;    // uniform address -> s_load
        #pragma unroll
        for (int j = 0; j < ALPHA; ++j)
            acc[j] = fmaf(xk, row[j], acc[j]);
    }

    // ---- Softmax over 26 (registers only) ----
    float m = acc[0];
    #pragma unroll
    for (int j = 1; j < ALPHA; ++j) m = fmaxf(m, acc[j]);
    float sum = 0.f;
    #pragma unroll
    for (int j = 0; j < ALPHA; ++j) { acc[j] = __expf(acc[j] - m); sum += acc[j]; }
    float inv = 1.0f / sum;
    #pragma unroll
    for (int j = 0; j < ALPHA; ++j) acc[j] *= inv;

    // ---- Stage results back through LDS, coalesced float2 store ----
    __syncthreads();   // everyone done reading x tile
    #pragma unroll
    for (int j = 0; j < ALPHA; ++j)
        tile[tid * TOK_PAD + j] = acc[j];
    __syncthreads();

    #pragma unroll
    for (int it = 0; it < 13; ++it) {
        int v = tid + it * TPB;
        int f = v * 2;
        int tok = f / ALPHA;
        int el = f - tok * ALPHA;
        float2 d;
        d.x = tile[tok * TOK_PAD + el];
        d.y = tile[tok * TOK_PAD + el + 1];
        *(float2*)(gout + f) = d;
    }
}

extern "C" void kernel_launch(void* const* d_in, const int* in_sizes, int n_in,
                              void* d_out, int out_size, void* d_ws, size_t ws_size,
                              hipStream_t stream) {
    const float* x     = (const float*)d_in[0];   // [128, 8192, 26] fp32
    const float* rotor = (const float*)d_in[1];   // [26, 26] fp32
    float* out = (float*)d_out;                   // [128, 8192, 26] fp32
    float* rn  = (float*)d_ws;                    // 26*32 floats = 3328 B

    rotor_norm_kernel<<<1, 64, 0, stream>>>(rotor, rn);

    const int tokens = out_size / ALPHA;          // 1,048,576
    const int blocks = tokens / TPB;              // 4096
    rotor_main<<<blocks, TPB, 0, stream>>>(x, rn, out);
}